// Round 10
// baseline (207.353 us; speedup 1.0000x reference)
//
#include <hip/hip_runtime.h>
#include <math.h>

#define FHW   32
#define NA    9
#define NBOX  9216          // 32*32*9
#define C1    256
#define C2    512
#define KTOT  2304          // 256*9
#define KS    8             // split-K factor
#define KCH   (KTOT / KS)   // 288
#define BK    16
#define NT    (KCH / BK)    // 18
#define CAP   64            // max stored out-neighbors per box (global)
#define CAPL  4             // LDS out-list stride (overflow -> global fallback)

struct AnchorWH { float w[NA]; float h[NA]; };

// ---------------- workspace layout (bytes, all 256-aligned) ----------------
// PROVEN footprint: total <= 24,154,116 B. Do not exceed.
#define FP_OFF    0u                      // padded feature 256*34*34 f32
#define WT_OFF    1183744u                // transposed weights 2304*512 f32 (tap-major rows)
#define HP_OFF    5902336u                // split-K partials 8*1024*512 f32
#define BOX_OFF   22679552u               // boxes 9216*4 f32
#define SC_OFF    22827008u               // scores 9216 f32
#define VL_OFF    22863872u               // vlist 9216 u32
#define DEG_OFF   22900736u               // deg 9216 u32 (in_cnt<<16 | out_cnt)
#define ADJ_OFF   22937600u               // adj 9216*CAP u16 (OUT-lists)
#define NV_OFF    24117248u               // valid count u32

// ---------------------------------------------------------------------------
// Kernel 1 (merged): blocks [0,1156): zero-pad feature into Fp[256][34][34],
// zero deg[]/nv, zero out[]. blocks [1156,2308): transpose conv1_w -> Wt,
// TAP-MAJOR rows k' = kap*256 + ch  (kap = 3*dy+dx).
// ---------------------------------------------------------------------------
__global__ __launch_bounds__(256) void k_prep(const float* __restrict__ fin,
                                              float* __restrict__ Fp,
                                              unsigned int* __restrict__ deg,
                                              unsigned int* __restrict__ nv,
                                              const float* __restrict__ w1,
                                              float* __restrict__ Wt,
                                              float* __restrict__ out) {
    if (blockIdx.x < 1156) {
        int idx = blockIdx.x * 256 + threadIdx.x;
        if (idx < 256 * 34 * 34) {
            int c   = idx / 1156;
            int rem = idx - c * 1156;
            int yy  = rem / 34;
            int xx  = rem - yy * 34;
            float v = 0.f;
            if (yy >= 1 && yy <= 32 && xx >= 1 && xx <= 32)
                v = fin[c * 1024 + (yy - 1) * 32 + (xx - 1)];
            Fp[idx] = v;
        }
        if (idx < NBOX)     deg[idx] = 0u;
        if (idx < NBOX * 5) out[idx] = 0.f;
        if (idx == 0)       *nv = 0u;
    } else {
        __shared__ float tile[32][33];
        int tb  = blockIdx.x - 1156;      // 72*16 tiles
        int k0  = (tb % 72) * 32;
        int oc0 = (tb / 72) * 32;
        int t   = threadIdx.x;
        int r0 = t >> 5, c = t & 31;
        #pragma unroll
        for (int i = 0; i < 4; ++i) {
            int r = r0 + 8 * i;                       // oc-local
            tile[r][c] = w1[(oc0 + r) * KTOT + k0 + c];
        }
        __syncthreads();
        #pragma unroll
        for (int i = 0; i < 4; ++i) {
            int kk  = r0 + 8 * i;                     // k-local
            int k   = k0 + kk;                        // source k = ch*9 + kap
            int ch  = k / 9;
            int kap = k - ch * 9;
            Wt[(kap * 256 + ch) * C2 + oc0 + c] = tile[c][kk];  // tap-major row
        }
    }
}

// ---------------------------------------------------------------------------
// Kernel 2: split-K fp32 GEMM. Tile 128x128, BK=16, 256 threads, 8x8 micro.
// Explicit ping-pong register pipeline across kk (load kk+1 fragments while
// computing kk) to hide ~120cyc ds_read latency at 1 wave/SIMD. Conflict-free
// LDS, 2 barriers/tile, reg prefetch of next K-tile. Grid 256, 1 block/CU.
// ---------------------------------------------------------------------------
__global__ __launch_bounds__(256) void k_gemm(const float* __restrict__ Fp,
                                              const float* __restrict__ Wt,
                                              float* __restrict__ hp) {
    const int id = blockIdx.x;             // 256 blocks: g(32) x kz(8)
    const int kz = id & 7;
    const int g  = id >> 3;                // 0..31
    const int by = g & 3, bx = g >> 2;     // 8 x 4 output tiles of 128x128
    const int p0  = bx * 128;
    const int oc0 = by * 128;
    const int k0b = kz * KCH;
    const int t  = threadIdx.x;
    const int ty = t >> 4, tx = t & 15;

    __shared__ float As[BK][128];          // 8 KB
    __shared__ float Bs[BK][128];          // 8 KB

    // staging coordinates (thread-constant)
    const int pp  = t & 127;               // A pixel-local; rows 2i + th
    const int th  = t >> 7;                // 0/1
    const int pyx = ((p0 + pp) >> 5) * 34 + ((p0 + pp) & 31);
    const int rB  = t >> 5;                // B k-local row base (0..7, +8)
    const int cB  = (t & 31) * 4;          // B col4 base

    float acc[2][2][4][4];
    #pragma unroll
    for (int rh = 0; rh < 2; ++rh)
        #pragma unroll
        for (int ch = 0; ch < 2; ++ch)
            #pragma unroll
            for (int r = 0; r < 4; ++r)
                #pragma unroll
                for (int c = 0; c < 4; ++c) acc[rh][ch][r][c] = 0.f;

    float  aS[8];
    float4 bS0, bS1;

    auto LOAD = [&](int s) {
        int tap = s >> 8, c0 = s & 255;
        int dy  = (tap * 11) >> 5;         // tap/3 for tap<9
        int dx  = tap - 3 * dy;
        const float* ab = Fp + ((c0 + th) * 34 + dy) * 34 + dx + pyx;
        #pragma unroll
        for (int i = 0; i < 8; ++i) aS[i] = ab[i * 2312];     // 2 channels apart
        const float* bb = Wt + (s + rB) * C2 + oc0 + cB;
        bS0 = *(const float4*)bb;
        bS1 = *(const float4*)(bb + 8 * C2);
    };
    auto STORE = [&]() {
        #pragma unroll
        for (int i = 0; i < 8; ++i) As[2 * i + th][pp] = aS[i];
        *(float4*)&Bs[rB][cB]     = bS0;
        *(float4*)&Bs[rB + 8][cB] = bS1;
    };

    float a0[2][4], b0[2][4], a1[2][4], b1[2][4];
    auto LDA = [&](float (&d)[2][4], int kk) {
        *(float4*)&d[0][0] = *(const float4*)&As[kk][ty * 4];
        *(float4*)&d[1][0] = *(const float4*)&As[kk][ty * 4 + 64];
    };
    auto LDB = [&](float (&d)[2][4], int kk) {
        *(float4*)&d[0][0] = *(const float4*)&Bs[kk][tx * 4];
        *(float4*)&d[1][0] = *(const float4*)&Bs[kk][tx * 4 + 64];
    };
    auto FMA = [&](const float (&a)[2][4], const float (&b)[2][4]) {
        #pragma unroll
        for (int rh = 0; rh < 2; ++rh)
            #pragma unroll
            for (int ch = 0; ch < 2; ++ch)
                #pragma unroll
                for (int r = 0; r < 4; ++r)
                    #pragma unroll
                    for (int c = 0; c < 4; ++c)
                        acc[rh][ch][r][c] = fmaf(a[rh][r], b[ch][c], acc[rh][ch][r][c]);
    };

    LOAD(k0b);
    #pragma unroll 1
    for (int tile = 0; tile < NT; ++tile) {
        __syncthreads();                   // prior compute done reading LDS
        STORE();
        __syncthreads();                   // staging visible
        if (tile + 1 < NT) LOAD(k0b + (tile + 1) * BK);   // global in flight
        LDA(a0, 0); LDB(b0, 0);
        #pragma unroll
        for (int kk = 0; kk < BK; kk += 2) {
            LDA(a1, kk + 1); LDB(b1, kk + 1);   // next frags during FMA(kk)
            FMA(a0, b0);
            if (kk + 2 < BK) { LDA(a0, kk + 2); LDB(b0, kk + 2); }
            FMA(a1, b1);
        }
    }

    #pragma unroll
    for (int rh = 0; rh < 2; ++rh)
        #pragma unroll
        for (int r = 0; r < 4; ++r) {
            int p = p0 + rh * 64 + ty * 4 + r;
            float* dst = hp + ((size_t)(kz * 1024 + p)) * C2 + oc0 + tx * 4;
            *(float4*)dst        = *(float4*)&acc[rh][0][r][0];
            *(float4*)(dst + 64) = *(float4*)&acc[rh][1][r][0];
        }
}

// ---------------------------------------------------------------------------
// Kernel 3: heads, 4 pixels/block (256 blocks). Split-K reduce + relu ->
// 45 dots/pixel -> sigmoid/decode/clip/valid -> compact valid list.
// ---------------------------------------------------------------------------
__global__ __launch_bounds__(256) void k_heads(const float* __restrict__ hp,
                                               const float* __restrict__ b1,
                                               const float* __restrict__ w2,
                                               const float* __restrict__ b2,
                                               const float* __restrict__ w3,
                                               const float* __restrict__ b3,
                                               float* __restrict__ boxes,
                                               float* __restrict__ scoresG,
                                               unsigned int* __restrict__ nv,
                                               unsigned int* __restrict__ vlist,
                                               AnchorWH awh) {
    const int p0 = blockIdx.x * 4;
    const int t  = threadIdx.x;
    __shared__ float hrow[4][C2];
    __shared__ float arr[4][45];

    #pragma unroll
    for (int px = 0; px < 4; ++px) {
        int p = p0 + px;
        #pragma unroll
        for (int i = 0; i < 2; ++i) {
            int c = t + 256 * i;
            float s = b1[c];
            #pragma unroll
            for (int ks = 0; ks < KS; ++ks) s += hp[((size_t)(ks * 1024 + p)) * C2 + c];
            hrow[px][c] = fmaxf(s, 0.f);
        }
    }
    __syncthreads();

    const int w = t >> 6, lane = t & 63;
    for (int job = w; job < 180; job += 4) {
        int px = job / 45, j = job - px * 45;
        const float* wp = (j < 9) ? (w2 + j * C2) : (w3 + (j - 9) * C2);
        float s = 0.f;
        #pragma unroll
        for (int i = 0; i < 8; ++i) s += hrow[px][lane + 64 * i] * wp[lane + 64 * i];
        #pragma unroll
        for (int d = 1; d < 64; d <<= 1) s += __shfl_xor(s, d, 64);
        if (lane == 0) arr[px][j] = s;
    }
    __syncthreads();

    if (t < 36) {
        int px = t / 9, a = t - px * 9;
        int p = p0 + px;
        float logit = arr[px][a] + b2[a];
        float score = 1.f / (1.f + expf(-logit));
        float o0 = arr[px][9 + a * 4 + 0] + b3[a * 4 + 0];
        float o1 = arr[px][9 + a * 4 + 1] + b3[a * 4 + 1];
        float o2 = arr[px][9 + a * 4 + 2] + b3[a * 4 + 2];
        float o3 = arr[px][9 + a * 4 + 3] + b3[a * 4 + 3];
        int y = p >> 5, x = p & 31;
        float ax = (x + 0.5f) * 16.f, ay = (y + 0.5f) * 16.f;
        float aw = awh.w[a], ah = awh.h[a];
        float cx = ax + o0 * aw;
        float cy = ay + o1 * ah;
        float bw = aw * expf(o2);
        float bh = ah * expf(o3);
        float x1 = fminf(fmaxf(cx - bw * 0.5f, 0.f), 512.f);
        float y1 = fminf(fmaxf(cy - bh * 0.5f, 0.f), 512.f);
        float x2 = fminf(fmaxf(cx + bw * 0.5f, 0.f), 512.f);
        float y2 = fminf(fmaxf(cy + bh * 0.5f, 0.f), 512.f);
        int n = p * 9 + a;
        float4 bx4; bx4.x = x1; bx4.y = y1; bx4.z = x2; bx4.w = y2;
        ((float4*)boxes)[n] = bx4;
        scoresG[n] = score;
        bool valid = (x2 - x1 >= 0.001f) && (y2 - y1 >= 0.001f) && (score >= 0.5f);
        if (valid) {
            unsigned int ci = atomicAdd(nv, 1u);
            vlist[ci] = (unsigned int)n;
        }
    }
}

// ---------------------------------------------------------------------------
// Kernel 4: sparse adjacency among valid boxes (IoU>0.7). OUT-lists (higher ->
// lower priority stored at the HIGHER node). deg packs in_cnt<<16 | out_cnt;
// in-count incremented only when the out-slot was stored (cap-consistent).
// Grid-stride over the EXACT pair-tile count (no dead blocks).
// ---------------------------------------------------------------------------
__global__ __launch_bounds__(256) void k_adj(const unsigned int* __restrict__ nvp,
                                             const unsigned int* __restrict__ vlist,
                                             const float* __restrict__ boxes,
                                             const float* __restrict__ scoresG,
                                             unsigned int* __restrict__ deg,
                                             unsigned short* __restrict__ adj) {
    const int Nv = (int)*nvp;
    const int T  = (Nv + 127) >> 7;
    const int NP = T * (T + 1) / 2;
    int t = threadIdx.x;

    __shared__ float4 ub[128], vb[128];
    __shared__ float  us[128], vs[128];
    __shared__ int    uo[128], vo[128];

    for (int b = blockIdx.x; b < NP; b += gridDim.x) {
        int tv = (int)(sqrtf(2.f * b + 0.25f) - 0.5f);
        while ((tv + 1) * (tv + 2) / 2 <= b) tv++;
        while (tv * (tv + 1) / 2 > b) tv--;
        int tu = b - tv * (tv + 1) / 2;

        if (t < 128) {
            int gi = tu * 128 + t;
            if (gi < Nv) { int n = (int)vlist[gi]; ub[t] = ((const float4*)boxes)[n]; us[t] = scoresG[n]; uo[t] = n; }
            else us[t] = -1.f;
        } else {
            int tt = t - 128;
            int gj = tv * 128 + tt;
            if (gj < Nv) { int n = (int)vlist[gj]; vb[tt] = ((const float4*)boxes)[n]; vs[tt] = scoresG[n]; vo[tt] = n; }
            else vs[tt] = -1.f;
        }
        __syncthreads();

        for (int s = 0; s < 64; ++s) {
            int q  = t + 256 * s;          // 16384 pairs
            int i  = q >> 7, jj = q & 127;
            if (tu == tv && i >= jj) continue;
            float su = us[i], sv = vs[jj];
            if (su < 0.f || sv < 0.f) continue;
            float4 bu = ub[i], bv = vb[jj];
            float au = (bu.z - bu.x) * (bu.w - bu.y);
            float av = (bv.z - bv.x) * (bv.w - bv.y);
            float ix1 = fmaxf(bu.x, bv.x), iy1 = fmaxf(bu.y, bv.y);
            float ix2 = fminf(bu.z, bv.z), iy2 = fminf(bu.w, bv.w);
            float inter = fmaxf(ix2 - ix1, 0.f) * fmaxf(iy2 - iy1, 0.f);
            float uni = au + av - inter;
            float iou = inter / fmaxf(uni, 1e-9f);
            if (iou > 0.7f) {
                int gi = tu * 128 + i, gj = tv * 128 + jj;
                bool uHigh = (su > sv) || (su == sv && uo[i] < vo[jj]);
                int hi = uHigh ? gi : gj;
                int lo = uHigh ? gj : gi;
                unsigned int old = atomicAdd(&deg[hi], 1u);
                if ((old & 0xFFFFu) < CAP) {
                    adj[hi * CAP + (old & 0xFFFFu)] = (unsigned short)lo;
                    atomicAdd(&deg[lo], 0x10000u);
                }
            }
        }
        __syncthreads();                   // LDS reuse safe for next pair-tile
    }
}

// ---------------------------------------------------------------------------
// Kernel 5: counter-based MIS peel (round-8 proven structure) + LDS dout.
// Per-node LDS word = sup_cnt<<16 | undecided_in_cnt. A decided node pushes
// ONE LDS atomicAdd per out-edge: kept -> +0xFFFF, suppressed -> -1.
// Decidable when cnt==0: kept iff sup==0. Owners poll 1 u32 per active node
// in WAVE-UNIFORM loops (no per-lane spin deps -> no SIMT deadlock).
// NEW vs r8: out-degree cached in LDS (doutL) so the chain's critical path
// has NO dependent global read (r8 re-read degG per push, ~600cyc/hop).
// ---------------------------------------------------------------------------
__global__ __launch_bounds__(512) void k_peel(const unsigned int* __restrict__ nvp,
                                              const unsigned int* __restrict__ vlist,
                                              const unsigned int* __restrict__ degG,
                                              const unsigned short* __restrict__ adjG,
                                              const float* __restrict__ boxes,
                                              const float* __restrict__ scoresG,
                                              float* __restrict__ out) {
    __shared__ unsigned int   word[NBOX];          // 36864 B
    __shared__ unsigned char  st[NBOX];            // 9216 B
    __shared__ unsigned char  doutL[NBOX];         // 9216 B
    __shared__ unsigned short outL[NBOX * CAPL];   // 73728 B   (total 129024)
    const int t  = threadIdx.x;
    const int Nv = (int)*nvp;
    const int chunk = (Nv + 511) / 512;            // <= 18
    const int i0 = t * chunk;
    const int i1 = (i0 + chunk < Nv) ? (i0 + chunk) : Nv;

    // ---- init: word=cin, LDS out-lists + out-degree, build masks ----
    unsigned int amask = 0, smask = 0;
    for (int i = i0; i < i1; ++i) {
        unsigned int dg = degG[i];
        unsigned int cin = dg >> 16;
        int dout = (int)(dg & 0xFFFFu); if (dout > CAP) dout = CAP;
        doutL[i] = (unsigned char)dout;
        int dl = (dout < CAPL) ? dout : CAPL;
        for (int s = 0; s < dl; ++s)
            outL[i * CAPL + s] = adjG[i * CAP + s];
        word[i] = cin;
        st[i] = 0;
        if (cin == 0u) smask |= 1u << (i - i0);    // local max -> kept seed
        else           amask |= 1u << (i - i0);
    }
    __syncthreads();

    // push decision of node i to its out-neighbors (all-LDS fast path)
    auto PUSH = [&](int i, bool kept) {
        int dout = (int)doutL[i];
        unsigned int delta = kept ? 0xFFFFu : 0xFFFFFFFFu;
        for (int s = 0; s < dout; ++s) {
            int j = (s < CAPL) ? (int)outL[i * CAPL + s]
                               : (int)adjG[i * CAP + s];
            atomicAdd(&word[j], delta);
        }
    };

    // ---- seeds: cin==0 nodes are kept, push now ----
    {
        unsigned int m = smask;
        while (m) {
            int b = __ffs(m) - 1; m &= m - 1;
            int i = i0 + b;
            st[i] = 1;
            PUSH(i, true);
        }
    }

    // ---- poll loop (wave-uniform): 1 LDS load per active node per sweep ----
    {
        volatile unsigned int* vw = word;
        int idle = 0;
        while (__any(amask != 0u)) {
            bool prog = false;
            unsigned int m = amask;
            while (m) {
                int b = __ffs(m) - 1; m &= m - 1;
                int i = i0 + b;
                unsigned int w = vw[i];
                if ((w & 0xFFFFu) == 0u) {
                    bool kept = (w >> 16) == 0u;
                    st[i] = kept ? 1 : 2;
                    PUSH(i, kept);
                    amask &= ~(1u << b);
                    prog = true;
                }
            }
            if (__any(prog)) idle = 0;
            else {
                if (++idle > 8000) break;          // paranoia guard
                __builtin_amdgcn_s_sleep(1);
            }
        }
    }
    __syncthreads();

    // ---- write kept rows of output (out pre-zeroed by k_prep) ----
    for (int i = i0; i < i1; ++i) {
        if (st[i] == 1) {
            int n = (int)vlist[i];
            float4 b = ((const float4*)boxes)[n];
            out[n * 5 + 0] = b.x;
            out[n * 5 + 1] = b.y;
            out[n * 5 + 2] = b.z;
            out[n * 5 + 3] = b.w;
            out[n * 5 + 4] = scoresG[n];
        }
    }
}

// ---------------------------------------------------------------------------
extern "C" void kernel_launch(void* const* d_in, const int* in_sizes, int n_in,
                              void* d_out, int out_size, void* d_ws, size_t ws_size,
                              hipStream_t stream) {
    const float* fin = (const float*)d_in[0];
    const float* w1  = (const float*)d_in[1];
    const float* b1  = (const float*)d_in[2];
    const float* w2  = (const float*)d_in[3];
    const float* b2  = (const float*)d_in[4];
    const float* w3  = (const float*)d_in[5];
    const float* b3  = (const float*)d_in[6];
    float* out = (float*)d_out;

    char* ws = (char*)d_ws;
    float*          Fp    = (float*)(ws + FP_OFF);
    float*          Wt    = (float*)(ws + WT_OFF);
    float*          hp    = (float*)(ws + HP_OFF);
    float*          boxes = (float*)(ws + BOX_OFF);
    float*          sc    = (float*)(ws + SC_OFF);
    unsigned int*   vlist = (unsigned int*)(ws + VL_OFF);
    unsigned int*   deg   = (unsigned int*)(ws + DEG_OFF);
    unsigned short* adj   = (unsigned short*)(ws + ADJ_OFF);
    unsigned int*   nv    = (unsigned int*)(ws + NV_OFF);

    AnchorWH awh;
    {
        const double sizes[3]  = {32.0, 64.0, 128.0};
        const double ratios[3] = {0.5, 1.0, 2.0};
        for (int si = 0; si < 3; ++si)
            for (int ri = 0; ri < 3; ++ri) {
                awh.w[si * 3 + ri] = (float)(sizes[si] / sqrt(ratios[ri]));
                awh.h[si * 3 + ri] = (float)(sizes[si] * sqrt(ratios[ri]));
            }
    }

    k_prep<<<dim3(1156 + 72 * 16), 256, 0, stream>>>(fin, Fp, deg, nv, w1, Wt, out);
    k_gemm<<<dim3(256), 256, 0, stream>>>(Fp, Wt, hp);
    k_heads<<<dim3(256), 256, 0, stream>>>(hp, b1, w2, b2, w3, b3, boxes, sc, nv, vlist, awh);
    k_adj<<<dim3(512), 256, 0, stream>>>(nv, vlist, boxes, sc, deg, adj);
    k_peel<<<dim3(1), 512, 0, stream>>>(nv, vlist, deg, adj, boxes, sc, out);
}

// Round 11
// 189.410 us; speedup vs baseline: 1.0947x; 1.0947x over previous
//
#include <hip/hip_runtime.h>
#include <math.h>

#define FHW   32
#define NA    9
#define NBOX  9216          // 32*32*9
#define C1    256
#define C2    512
#define KTOT  2304          // 256*9
#define BK    16
#define CAP   64            // max stored out-neighbors per box (global)
#define CAPL  4             // LDS out-list stride (overflow -> global fallback)

struct AnchorWH { float w[NA]; float h[NA]; };

// ---------------- workspace layout ----------------
// Fixed prefix: FP 0..1183744, WT ..5902336, HP ..(+KSd*2MB).
// KSd=8 layout == proven 24.15MB footprint (r5-r10). KSd=16 (40.9MB) only
// taken when ws_size PROVES capacity; ws_size==0 -> conservative KSd=8.
#define FP_OFF    0u
#define WT_OFF    1183744u
#define HP_OFF    5902336u

// ---------------------------------------------------------------------------
// Kernel 1 (merged): blocks [0,1156): zero-pad feature into Fp[256][34][34],
// zero deg[]/nv, zero out[]. blocks [1156,2308): transpose conv1_w -> Wt,
// TAP-MAJOR rows k' = kap*256 + ch  (kap = 3*dy+dx).
// ---------------------------------------------------------------------------
__global__ __launch_bounds__(256) void k_prep(const float* __restrict__ fin,
                                              float* __restrict__ Fp,
                                              unsigned int* __restrict__ deg,
                                              unsigned int* __restrict__ nv,
                                              const float* __restrict__ w1,
                                              float* __restrict__ Wt,
                                              float* __restrict__ out) {
    if (blockIdx.x < 1156) {
        int idx = blockIdx.x * 256 + threadIdx.x;
        if (idx < 256 * 34 * 34) {
            int c   = idx / 1156;
            int rem = idx - c * 1156;
            int yy  = rem / 34;
            int xx  = rem - yy * 34;
            float v = 0.f;
            if (yy >= 1 && yy <= 32 && xx >= 1 && xx <= 32)
                v = fin[c * 1024 + (yy - 1) * 32 + (xx - 1)];
            Fp[idx] = v;
        }
        if (idx < NBOX)     deg[idx] = 0u;
        if (idx < NBOX * 5) out[idx] = 0.f;
        if (idx == 0)       *nv = 0u;
    } else {
        __shared__ float tile[32][33];
        int tb  = blockIdx.x - 1156;      // 72*16 tiles
        int k0  = (tb % 72) * 32;
        int oc0 = (tb / 72) * 32;
        int t   = threadIdx.x;
        int r0 = t >> 5, c = t & 31;
        #pragma unroll
        for (int i = 0; i < 4; ++i) {
            int r = r0 + 8 * i;                       // oc-local
            tile[r][c] = w1[(oc0 + r) * KTOT + k0 + c];
        }
        __syncthreads();
        #pragma unroll
        for (int i = 0; i < 4; ++i) {
            int kk  = r0 + 8 * i;                     // k-local
            int k   = k0 + kk;                        // source k = ch*9 + kap
            int ch  = k / 9;
            int kap = k - ch * 9;
            Wt[(kap * 256 + ch) * C2 + oc0 + c] = tile[c][kk];  // tap-major row
        }
    }
}

// ---------------------------------------------------------------------------
// Kernel 2: split-K fp32 GEMM, KS parameterized (8 or 16 via kshift).
// Tile 128x128, BK=16, 256 threads, 8x8 micro with +-64 split rows/cols
// (conflict-free LDS). Single 16KB LDS buffer, 2 barriers/tile, register
// prefetch of next K-tile. KS=16 -> 512 blocks = 2 blocks/CU = 2 waves/SIMD:
// TLP finally covers barrier/vmcnt stalls that pinned KS=8 at ~45us.
// Body is the r5-proven one; only kz/g/KCH derive from kshift.
// ---------------------------------------------------------------------------
__global__ __launch_bounds__(256) void k_gemm(const float* __restrict__ Fp,
                                              const float* __restrict__ Wt,
                                              float* __restrict__ hp,
                                              int kshift) {
    const int KCHd  = KTOT >> kshift;      // 288 (KS8) / 144 (KS16)
    const int NTd   = KCHd >> 4;           // 18 / 9 tiles
    const int kmask = (1 << kshift) - 1;
    const int id = blockIdx.x;
    const int kz = id & kmask;             // id%NXCD groups same-kz on an XCD
    const int g  = id >> kshift;           // 0..31
    const int by = g & 3, bx = g >> 2;     // 8 x 4 output tiles of 128x128
    const int p0  = bx * 128;
    const int oc0 = by * 128;
    const int k0b = kz * KCHd;
    const int t  = threadIdx.x;
    const int ty = t >> 4, tx = t & 15;

    __shared__ float As[BK][128];          // 8 KB
    __shared__ float Bs[BK][128];          // 8 KB

    const int pp  = t & 127;               // A pixel-local; rows 2i + th
    const int th  = t >> 7;                // 0/1
    const int pyx = ((p0 + pp) >> 5) * 34 + ((p0 + pp) & 31);
    const int rB  = t >> 5;                // B k-local row base (0..7, +8)
    const int cB  = (t & 31) * 4;          // B col4 base

    float acc[2][2][4][4];
    #pragma unroll
    for (int rh = 0; rh < 2; ++rh)
        #pragma unroll
        for (int ch = 0; ch < 2; ++ch)
            #pragma unroll
            for (int r = 0; r < 4; ++r)
                #pragma unroll
                for (int c = 0; c < 4; ++c) acc[rh][ch][r][c] = 0.f;

    float  aS[8];
    float4 bS0, bS1;

    // gather K-tile at tap-major index s (multiple of 16 -> uniform tap)
    auto LOAD = [&](int s) {
        int tap = s >> 8, c0 = s & 255;
        int dy  = (tap * 11) >> 5;         // tap/3 for tap<9
        int dx  = tap - 3 * dy;
        const float* ab = Fp + ((c0 + th) * 34 + dy) * 34 + dx + pyx;
        #pragma unroll
        for (int i = 0; i < 8; ++i) aS[i] = ab[i * 2312];     // 2 channels apart
        const float* bb = Wt + (s + rB) * C2 + oc0 + cB;
        bS0 = *(const float4*)bb;
        bS1 = *(const float4*)(bb + 8 * C2);
    };
    auto STORE = [&]() {
        #pragma unroll
        for (int i = 0; i < 8; ++i) As[2 * i + th][pp] = aS[i];
        *(float4*)&Bs[rB][cB]     = bS0;
        *(float4*)&Bs[rB + 8][cB] = bS1;
    };

    LOAD(k0b);
    #pragma unroll 1
    for (int tile = 0; tile < NTd; ++tile) {
        __syncthreads();                   // prior compute done reading LDS
        STORE();
        __syncthreads();                   // staging visible
        if (tile + 1 < NTd) LOAD(k0b + (tile + 1) * BK);  // in flight over FMAs
        #pragma unroll
        for (int kk = 0; kk < BK; ++kk) {
            float a[2][4], b[2][4];
            *(float4*)&a[0][0] = *(const float4*)&As[kk][ty * 4];
            *(float4*)&a[1][0] = *(const float4*)&As[kk][ty * 4 + 64];
            *(float4*)&b[0][0] = *(const float4*)&Bs[kk][tx * 4];
            *(float4*)&b[1][0] = *(const float4*)&Bs[kk][tx * 4 + 64];
            #pragma unroll
            for (int rh = 0; rh < 2; ++rh)
                #pragma unroll
                for (int ch = 0; ch < 2; ++ch)
                    #pragma unroll
                    for (int r = 0; r < 4; ++r)
                        #pragma unroll
                        for (int c = 0; c < 4; ++c)
                            acc[rh][ch][r][c] = fmaf(a[rh][r], b[ch][c], acc[rh][ch][r][c]);
        }
    }

    #pragma unroll
    for (int rh = 0; rh < 2; ++rh)
        #pragma unroll
        for (int r = 0; r < 4; ++r) {
            int p = p0 + rh * 64 + ty * 4 + r;
            float* dst = hp + ((size_t)(kz * 1024 + p)) * C2 + oc0 + tx * 4;
            *(float4*)dst        = *(float4*)&acc[rh][0][r][0];
            *(float4*)(dst + 64) = *(float4*)&acc[rh][1][r][0];
        }
}

// ---------------------------------------------------------------------------
// Kernel 3: heads, 4 pixels/block (256 blocks).
// Phase 1 now float4 (was 64 scalar loads/thread): 2 px-groups x 128 c4-lanes.
// Phase 2 now 16-lane-group dots (16 groups/block, 12 rounds; shfl 270->48
// per wave). Phase 3 unchanged.
// ---------------------------------------------------------------------------
__global__ __launch_bounds__(256) void k_heads(const float* __restrict__ hp,
                                               const float* __restrict__ b1,
                                               const float* __restrict__ w2,
                                               const float* __restrict__ b2,
                                               const float* __restrict__ w3,
                                               const float* __restrict__ b3,
                                               float* __restrict__ boxes,
                                               float* __restrict__ scoresG,
                                               unsigned int* __restrict__ nv,
                                               unsigned int* __restrict__ vlist,
                                               AnchorWH awh, int KSd) {
    const int p0 = blockIdx.x * 4;
    const int t  = threadIdx.x;
    __shared__ float hrow[4][C2];
    __shared__ float arr[4][45];

    // ---- phase 1: split-K reduce + relu (float4) ----
    {
        const int c4 = t & 127;            // float4 lane
        const int ph = t >> 7;             // 0/1
        #pragma unroll
        for (int px2 = 0; px2 < 2; ++px2) {
            int px = px2 * 2 + ph;
            int p  = p0 + px;
            float4 s = ((const float4*)b1)[c4];
            for (int ks = 0; ks < KSd; ++ks) {
                float4 v = ((const float4*)hp)[(size_t)(ks * 1024 + p) * 128 + c4];
                s.x += v.x; s.y += v.y; s.z += v.z; s.w += v.w;
            }
            s.x = fmaxf(s.x, 0.f); s.y = fmaxf(s.y, 0.f);
            s.z = fmaxf(s.z, 0.f); s.w = fmaxf(s.w, 0.f);
            *(float4*)&hrow[px][c4 * 4] = s;
        }
    }
    __syncthreads();

    // ---- phase 2: 180 dot products, 16-lane groups ----
    {
        const int grp = t >> 4, l = t & 15;
        for (int r = 0; r < 12; ++r) {
            int j180 = grp + (r << 4);
            float s = 0.f;
            int px = 0, j = 0;
            if (j180 < 180) {
                px = j180 / 45; j = j180 - px * 45;
                const float* wp = (j < 9) ? (w2 + j * C2) : (w3 + (j - 9) * C2);
                #pragma unroll
                for (int i = 0; i < 32; ++i)
                    s += hrow[px][l + 16 * i] * wp[l + 16 * i];
            }
            s += __shfl_xor(s, 1, 16);
            s += __shfl_xor(s, 2, 16);
            s += __shfl_xor(s, 4, 16);
            s += __shfl_xor(s, 8, 16);
            if (j180 < 180 && l == 0) arr[px][j] = s;
        }
    }
    __syncthreads();

    if (t < 36) {
        int px = t / 9, a = t - px * 9;
        int p = p0 + px;
        float logit = arr[px][a] + b2[a];
        float score = 1.f / (1.f + expf(-logit));
        float o0 = arr[px][9 + a * 4 + 0] + b3[a * 4 + 0];
        float o1 = arr[px][9 + a * 4 + 1] + b3[a * 4 + 1];
        float o2 = arr[px][9 + a * 4 + 2] + b3[a * 4 + 2];
        float o3 = arr[px][9 + a * 4 + 3] + b3[a * 4 + 3];
        int y = p >> 5, x = p & 31;
        float ax = (x + 0.5f) * 16.f, ay = (y + 0.5f) * 16.f;
        float aw = awh.w[a], ah = awh.h[a];
        float cx = ax + o0 * aw;
        float cy = ay + o1 * ah;
        float bw = aw * expf(o2);
        float bh = ah * expf(o3);
        float x1 = fminf(fmaxf(cx - bw * 0.5f, 0.f), 512.f);
        float y1 = fminf(fmaxf(cy - bh * 0.5f, 0.f), 512.f);
        float x2 = fminf(fmaxf(cx + bw * 0.5f, 0.f), 512.f);
        float y2 = fminf(fmaxf(cy + bh * 0.5f, 0.f), 512.f);
        int n = p * 9 + a;
        float4 bx4; bx4.x = x1; bx4.y = y1; bx4.z = x2; bx4.w = y2;
        ((float4*)boxes)[n] = bx4;
        scoresG[n] = score;
        bool valid = (x2 - x1 >= 0.001f) && (y2 - y1 >= 0.001f) && (score >= 0.5f);
        if (valid) {
            unsigned int ci = atomicAdd(nv, 1u);
            vlist[ci] = (unsigned int)n;
        }
    }
}

// ---------------------------------------------------------------------------
// Kernel 4: sparse adjacency among valid boxes (IoU>0.7). OUT-lists (higher ->
// lower priority stored at the HIGHER node). deg packs in_cnt<<16 | out_cnt;
// in-count incremented only when the out-slot was stored. Grid-stride.
// ---------------------------------------------------------------------------
__global__ __launch_bounds__(256) void k_adj(const unsigned int* __restrict__ nvp,
                                             const unsigned int* __restrict__ vlist,
                                             const float* __restrict__ boxes,
                                             const float* __restrict__ scoresG,
                                             unsigned int* __restrict__ deg,
                                             unsigned short* __restrict__ adj) {
    const int Nv = (int)*nvp;
    const int T  = (Nv + 127) >> 7;
    const int NP = T * (T + 1) / 2;
    int t = threadIdx.x;

    __shared__ float4 ub[128], vb[128];
    __shared__ float  us[128], vs[128];
    __shared__ int    uo[128], vo[128];

    for (int b = blockIdx.x; b < NP; b += gridDim.x) {
        int tv = (int)(sqrtf(2.f * b + 0.25f) - 0.5f);
        while ((tv + 1) * (tv + 2) / 2 <= b) tv++;
        while (tv * (tv + 1) / 2 > b) tv--;
        int tu = b - tv * (tv + 1) / 2;

        if (t < 128) {
            int gi = tu * 128 + t;
            if (gi < Nv) { int n = (int)vlist[gi]; ub[t] = ((const float4*)boxes)[n]; us[t] = scoresG[n]; uo[t] = n; }
            else us[t] = -1.f;
        } else {
            int tt = t - 128;
            int gj = tv * 128 + tt;
            if (gj < Nv) { int n = (int)vlist[gj]; vb[tt] = ((const float4*)boxes)[n]; vs[tt] = scoresG[n]; vo[tt] = n; }
            else vs[tt] = -1.f;
        }
        __syncthreads();

        for (int s = 0; s < 64; ++s) {
            int q  = t + 256 * s;          // 16384 pairs
            int i  = q >> 7, jj = q & 127;
            if (tu == tv && i >= jj) continue;
            float su = us[i], sv = vs[jj];
            if (su < 0.f || sv < 0.f) continue;
            float4 bu = ub[i], bv = vb[jj];
            float au = (bu.z - bu.x) * (bu.w - bu.y);
            float av = (bv.z - bv.x) * (bv.w - bv.y);
            float ix1 = fmaxf(bu.x, bv.x), iy1 = fmaxf(bu.y, bv.y);
            float ix2 = fminf(bu.z, bv.z), iy2 = fminf(bu.w, bv.w);
            float inter = fmaxf(ix2 - ix1, 0.f) * fmaxf(iy2 - iy1, 0.f);
            float uni = au + av - inter;
            float iou = inter / fmaxf(uni, 1e-9f);
            if (iou > 0.7f) {
                int gi = tu * 128 + i, gj = tv * 128 + jj;
                bool uHigh = (su > sv) || (su == sv && uo[i] < vo[jj]);
                int hi = uHigh ? gi : gj;
                int lo = uHigh ? gj : gi;
                unsigned int old = atomicAdd(&deg[hi], 1u);
                if ((old & 0xFFFFu) < CAP) {
                    adj[hi * CAP + (old & 0xFFFFu)] = (unsigned short)lo;
                    atomicAdd(&deg[lo], 0x10000u);
                }
            }
        }
        __syncthreads();                   // LDS reuse safe for next pair-tile
    }
}

// ---------------------------------------------------------------------------
// Kernel 5: counter-based MIS peel (r8/r10-proven wave-uniform structure).
// word[i] = sup<<16 | cnt; kept-push +0xFFFF, sup-push -1; decidable at
// cnt==0 (kept iff sup==0). Busy-spin for first idle sweeps, then s_sleep.
// ---------------------------------------------------------------------------
__global__ __launch_bounds__(512) void k_peel(const unsigned int* __restrict__ nvp,
                                              const unsigned int* __restrict__ vlist,
                                              const unsigned int* __restrict__ degG,
                                              const unsigned short* __restrict__ adjG,
                                              const float* __restrict__ boxes,
                                              const float* __restrict__ scoresG,
                                              float* __restrict__ out) {
    __shared__ unsigned int   word[NBOX];          // 36864 B
    __shared__ unsigned char  st[NBOX];            // 9216 B
    __shared__ unsigned char  doutL[NBOX];         // 9216 B
    __shared__ unsigned short outL[NBOX * CAPL];   // 73728 B
    const int t  = threadIdx.x;
    const int Nv = (int)*nvp;
    const int chunk = (Nv + 511) / 512;            // <= 18
    const int i0 = t * chunk;
    const int i1 = (i0 + chunk < Nv) ? (i0 + chunk) : Nv;

    unsigned int amask = 0, smask = 0;
    for (int i = i0; i < i1; ++i) {
        unsigned int dg = degG[i];
        unsigned int cin = dg >> 16;
        int dout = (int)(dg & 0xFFFFu); if (dout > CAP) dout = CAP;
        doutL[i] = (unsigned char)dout;
        int dl = (dout < CAPL) ? dout : CAPL;
        for (int s = 0; s < dl; ++s)
            outL[i * CAPL + s] = adjG[i * CAP + s];
        word[i] = cin;
        st[i] = 0;
        if (cin == 0u) smask |= 1u << (i - i0);
        else           amask |= 1u << (i - i0);
    }
    __syncthreads();

    auto PUSH = [&](int i, bool kept) {
        int dout = (int)doutL[i];
        unsigned int delta = kept ? 0xFFFFu : 0xFFFFFFFFu;
        for (int s = 0; s < dout; ++s) {
            int j = (s < CAPL) ? (int)outL[i * CAPL + s]
                               : (int)adjG[i * CAP + s];
            atomicAdd(&word[j], delta);
        }
    };

    {
        unsigned int m = smask;
        while (m) {
            int b = __ffs(m) - 1; m &= m - 1;
            int i = i0 + b;
            st[i] = 1;
            PUSH(i, true);
        }
    }

    {
        volatile unsigned int* vw = word;
        int idle = 0;
        while (__any(amask != 0u)) {
            bool prog = false;
            unsigned int m = amask;
            while (m) {
                int b = __ffs(m) - 1; m &= m - 1;
                int i = i0 + b;
                unsigned int w = vw[i];
                if ((w & 0xFFFFu) == 0u) {
                    bool kept = (w >> 16) == 0u;
                    st[i] = kept ? 1 : 2;
                    PUSH(i, kept);
                    amask &= ~(1u << b);
                    prog = true;
                }
            }
            if (__any(prog)) idle = 0;
            else {
                ++idle;
                if (idle > 8000) break;            // paranoia guard
                if (idle > 2) __builtin_amdgcn_s_sleep(1);
            }
        }
    }
    __syncthreads();

    for (int i = i0; i < i1; ++i) {
        if (st[i] == 1) {
            int n = (int)vlist[i];
            float4 b = ((const float4*)boxes)[n];
            out[n * 5 + 0] = b.x;
            out[n * 5 + 1] = b.y;
            out[n * 5 + 2] = b.z;
            out[n * 5 + 3] = b.w;
            out[n * 5 + 4] = scoresG[n];
        }
    }
}

// ---------------------------------------------------------------------------
extern "C" void kernel_launch(void* const* d_in, const int* in_sizes, int n_in,
                              void* d_out, int out_size, void* d_ws, size_t ws_size,
                              hipStream_t stream) {
    const float* fin = (const float*)d_in[0];
    const float* w1  = (const float*)d_in[1];
    const float* b1  = (const float*)d_in[2];
    const float* w2  = (const float*)d_in[3];
    const float* b2  = (const float*)d_in[4];
    const float* w3  = (const float*)d_in[5];
    const float* b3  = (const float*)d_in[6];
    float* out = (float*)d_out;

    // KS choice: 16 only if workspace PROVES capacity (40,894,816 B needed).
    // ws_size==0 or small -> KS8 with the byte-identical proven 24.15MB layout.
    const size_t need16 = (size_t)HP_OFF + 33554432u
                        + 147456u + 3u * 36864u + 1179648u + 256u;  // 40,894,816
    int kshift = (ws_size >= need16) ? 4 : 3;
    int KSd = 1 << kshift;
    size_t hpB = (size_t)KSd * 1024 * C2 * 4;

    char* ws = (char*)d_ws;
    float*          Fp    = (float*)(ws + FP_OFF);
    float*          Wt    = (float*)(ws + WT_OFF);
    float*          hp    = (float*)(ws + HP_OFF);
    size_t o = HP_OFF + hpB;
    float*          boxes = (float*)(ws + o); o += (size_t)NBOX * 16;
    float*          sc    = (float*)(ws + o); o += (size_t)NBOX * 4;
    unsigned int*   vlist = (unsigned int*)(ws + o); o += (size_t)NBOX * 4;
    unsigned int*   deg   = (unsigned int*)(ws + o); o += (size_t)NBOX * 4;
    unsigned short* adj   = (unsigned short*)(ws + o); o += (size_t)NBOX * CAP * 2;
    unsigned int*   nv    = (unsigned int*)(ws + o);

    AnchorWH awh;
    {
        const double sizes[3]  = {32.0, 64.0, 128.0};
        const double ratios[3] = {0.5, 1.0, 2.0};
        for (int si = 0; si < 3; ++si)
            for (int ri = 0; ri < 3; ++ri) {
                awh.w[si * 3 + ri] = (float)(sizes[si] / sqrt(ratios[ri]));
                awh.h[si * 3 + ri] = (float)(sizes[si] * sqrt(ratios[ri]));
            }
    }

    k_prep<<<dim3(1156 + 72 * 16), 256, 0, stream>>>(fin, Fp, deg, nv, w1, Wt, out);
    k_gemm<<<dim3(32 * KSd), 256, 0, stream>>>(Fp, Wt, hp, kshift);
    k_heads<<<dim3(256), 256, 0, stream>>>(hp, b1, w2, b2, w3, b3, boxes, sc, nv, vlist, awh, KSd);
    k_adj<<<dim3(512), 256, 0, stream>>>(nv, vlist, boxes, sc, deg, adj);
    k_peel<<<dim3(1), 512, 0, stream>>>(nv, vlist, deg, adj, boxes, sc, out);
}